// Round 2
// baseline (1408.416 us; speedup 1.0000x reference)
//
#include <hip/hip_runtime.h>
#include <hip/hip_bf16.h>

typedef _Float16 f16;
typedef _Float16 half8 __attribute__((ext_vector_type(8)));
typedef float f32x4 __attribute__((ext_vector_type(4)));

// Problem constants: B=32, S=1024, D=256, H=256, 4H=1024, M=B*S=32768, Ncat=2048

// ---------------- prep: per-column int8 quantization of U (both dirs) -------
// UQ layout: dword index ((dir*16 + kkk)*1024 + j)*4 + e2, kkk=0..15, e2=0..3
// packs U rows k = 16*kkk + 4*e2 + byte  for column j.
__global__ void prep_uq_kernel(const float* __restrict__ Uf, const float* __restrict__ Ur,
                               unsigned int* __restrict__ UQ, float* __restrict__ Uscale)
{
    int idx = blockIdx.x * 256 + threadIdx.x;   // 0..2047 = (dir, j)
    if (idx >= 2048) return;
    int dir = idx >> 10, j = idx & 1023;
    const float* U = dir ? Ur : Uf;
    float m = 0.f;
    for (int k = 0; k < 256; ++k) m = fmaxf(m, fabsf(U[k * 1024 + j]));
    float sinv = (m > 0.f) ? 127.f / m : 0.f;
    for (int kk = 0; kk < 64; ++kk) {
        unsigned int w = 0;
        #pragma unroll
        for (int e = 0; e < 4; ++e) {
            float v = U[(kk * 4 + e) * 1024 + j];
            int q = __float2int_rn(v * sinv);
            w |= ((unsigned int)(q & 0xff)) << (8 * e);
        }
        UQ[(((size_t)dir * 16 + (kk >> 2)) * 1024 + j) * 4 + (kk & 3)] = w;
    }
    Uscale[idx] = m / (127.f * 127.f);  // combined U-scale * h-dequant(1/127)
}

// ---------------- projection GEMM: G[m][n'] = x[m]@W_dir + b_dir (f16) ------
// m = b*1024+s (NOT reversed; reverse handled by scan indexing), n' = dir*1024+g
__global__ __launch_bounds__(256) void proj_gemm_kernel(
    const float* __restrict__ x, const float* __restrict__ Wf, const float* __restrict__ Wr,
    const float* __restrict__ bfw, const float* __restrict__ brw, f16* __restrict__ G)
{
    const int nt = blockIdx.x;           // 0..15  (128-wide n tiles over 2048)
    const int mt = blockIdx.y;           // 0..255 (128-wide m tiles over 32768)
    const int m0 = mt * 128, n0 = nt * 128;
    const int dir = n0 >> 10, nin0 = n0 & 1023;
    const float* W   = dir ? Wr : Wf;
    const float* bia = dir ? brw : bfw;
    __shared__ f16 Asm[128][40];   // [row][k], pad 40 for bank spread
    __shared__ f16 Bsm[128][40];   // [col][k]
    const int t = threadIdx.x;
    const int lane = t & 63, wave = t >> 6;
    const int wr = wave >> 1, wc = wave & 1;      // 2x2 waves, 64x64 each
    f32x4 acc[4][4] = {};
    for (int k0 = 0; k0 < 256; k0 += 32) {
        #pragma unroll
        for (int e = 0; e < 16; ++e) {            // A: 128x32
            int idx = e * 256 + t;
            int r = idx >> 5, kk = idx & 31;
            Asm[r][kk] = (f16)x[(size_t)(m0 + r) * 256 + (k0 + kk)];
        }
        #pragma unroll
        for (int e = 0; e < 16; ++e) {            // B: 32x128 -> [col][k]
            int idx = e * 256 + t;
            int col = idx & 127, kr = idx >> 7;
            Bsm[col][kr] = (f16)W[(size_t)(k0 + kr) * 1024 + (nin0 + col)];
        }
        __syncthreads();
        const int l15 = lane & 15, kb = (lane >> 4) * 8;
        half8 af[4], bfr[4];
        #pragma unroll
        for (int fr = 0; fr < 4; ++fr) af[fr]  = *(const half8*)&Asm[wr * 64 + fr * 16 + l15][kb];
        #pragma unroll
        for (int fc = 0; fc < 4; ++fc) bfr[fc] = *(const half8*)&Bsm[wc * 64 + fc * 16 + l15][kb];
        #pragma unroll
        for (int fr = 0; fr < 4; ++fr)
            #pragma unroll
            for (int fc = 0; fc < 4; ++fc)
                acc[fr][fc] = __builtin_amdgcn_mfma_f32_16x16x32_f16(af[fr], bfr[fc], acc[fr][fc], 0, 0, 0);
        __syncthreads();
    }
    // epilogue: C/D map col=lane&15, row=(lane>>4)*4+i (m89-verified)
    const int row4 = (lane >> 4) * 4, c15 = lane & 15;
    #pragma unroll
    for (int fr = 0; fr < 4; ++fr)
        #pragma unroll
        for (int fc = 0; fc < 4; ++fc) {
            int rbase = m0 + wr * 64 + fr * 16 + row4;
            int cidx  = n0 + wc * 64 + fc * 16 + c15;
            float bv = bia[cidx & 1023];
            #pragma unroll
            for (int i = 0; i < 4; ++i)
                G[(size_t)(rbase + i) * 2048 + cidx] = (f16)(acc[fr][fc][i] + bv);
        }
}

// ---------------- persistent scan: 64 WGs = (dir, batch), 1024 thr ----------
__device__ __forceinline__ int dot4i8(unsigned int a, unsigned int b, int c) {
#if __has_builtin(__builtin_amdgcn_sdot4)
    return __builtin_amdgcn_sdot4(a, b, c, false);
#else
    c += (int)(signed char)(a)       * (int)(signed char)(b);
    c += (int)(signed char)(a >> 8)  * (int)(signed char)(b >> 8);
    c += (int)(signed char)(a >> 16) * (int)(signed char)(b >> 16);
    c += (int)(signed char)(a >> 24) * (int)(signed char)(b >> 24);
    return c;
#endif
}

// rotate values within each 4-lane quad: lane l gets lane ((l&~3)|((l+1)&3))'s value
__device__ __forceinline__ int quad_rot1(int v) {
#if __has_builtin(__builtin_amdgcn_mov_dpp)
    return __builtin_amdgcn_mov_dpp(v, 0x39 /*quad_perm [1,2,3,0]*/, 0xF, 0xF, true);
#else
    int l = threadIdx.x & 63;
    return __shfl(v, (l & ~3) | ((l + 1) & 3), 64);
#endif
}

__device__ __forceinline__ float tanh_fast(float x) {
    float e = __expf(2.f * x);
    return 1.f - 2.f / (e + 1.f);   // exact limits at +-inf, NaN-free
}

#define PIN4(u) asm volatile("" : "+v"(u.x), "+v"(u.y), "+v"(u.z), "+v"(u.w))

__global__ __launch_bounds__(1024, 4) void scan_kernel(
    const f16* __restrict__ G, const unsigned int* __restrict__ UQ,
    const float* __restrict__ Uscale, float* __restrict__ out)
{
    const int wg = blockIdx.x;
    const int dir = wg >> 5, b = wg & 31;
    const int g = threadIdx.x;                 // gate column 0..1023
    const int q = g & 3;                       // my h-quarter (via quad lane id)
    __shared__ __align__(16) unsigned int hq[64];   // h int8[256]
    __shared__ float preact[1024];

    // U column g resident in 64 VGPRs, slot order rotated per-thread so that
    // round r (which sees h-quarter (q+r)&3 after r quad-rotations) uses
    // compile-time register indices. Pinned via asm so the compiler cannot
    // demote to per-step reloads (round-1 showed VGPR=48 => U was re-streamed).
    uint4 ureg[16];
    #pragma unroll
    for (int r = 0; r < 4; ++r) {
        int p = (q + r) & 3;                   // h-quarter used in round r
        #pragma unroll
        for (int jj = 0; jj < 4; ++jj) {
            int kkk = p * 4 + jj;
            ureg[r * 4 + jj] = *(const uint4*)&UQ[(((size_t)dir * 16 + kkk) * 1024 + g) * 4];
            PIN4(ureg[r * 4 + jj]);
        }
    }
    const float usc = Uscale[dir * 1024 + g];

    // h quarter registers (16 dwords = 64 bytes of int8 h), start at h0 = 0
    int hd[16];
    #pragma unroll
    for (int m = 0; m < 16; ++m) hd[m] = 0;

    float c_state = 0.f;                       // valid for g < 256
    const f16* Grow = G + (size_t)b * 1024 * 2048 + dir * 1024 + g;
    float* outp = out + (size_t)b * 1024 * 512 + dir * 256 + g;  // used by g<256
    int s0 = dir ? 1023 : 0;
    f16 xw_c = Grow[(size_t)s0 * 2048];        // prefetch step 0
    __syncthreads();

    for (int t = 0; t < 1024; ++t) {
        int tn = (t < 1023) ? (t + 1) : t;
        int sn = dir ? (1023 - tn) : tn;
        f16 xw_n = Grow[(size_t)sn * 2048];    // prefetch next step's xW

        int i0 = 0, i1 = 0, i2 = 0, i3 = 0;    // 4 chains for ILP
        #pragma unroll
        for (int r = 0; r < 4; ++r) {
            #pragma unroll
            for (int jj = 0; jj < 4; ++jj) {
                const uint4 u = ureg[r * 4 + jj];
                i0 = dot4i8(u.x, hd[jj * 4 + 0], i0);
                i1 = dot4i8(u.y, hd[jj * 4 + 1], i1);
                i2 = dot4i8(u.z, hd[jj * 4 + 2], i2);
                i3 = dot4i8(u.w, hd[jj * 4 + 3], i3);
            }
            if (r < 3) {                       // rotate h quarters within quad
                #pragma unroll
                for (int m = 0; m < 16; ++m) hd[m] = quad_rot1(hd[m]);
            }
        }
        int iacc = (i0 + i1) + (i2 + i3);
        preact[g] = (float)xw_c + (float)iacc * usc;
        __syncthreads();

        if (g < 256) {
            float pi = preact[g];
            float pf = preact[256 + g];
            float pg = preact[512 + g];
            float po = preact[768 + g];
            float ig = 1.f / (1.f + __expf(-pi));
            float fg = 1.f / (1.f + __expf(-pf));
            float gg = tanh_fast(pg);
            float og = 1.f / (1.f + __expf(-po));
            c_state = fg * c_state + ig * gg;
            float h = og * tanh_fast(c_state);
            int s = dir ? (1023 - t) : t;
            outp[(size_t)s * 512] = h;
            int iq = __float2int_rn(h * 127.f);
            ((signed char*)hq)[g] = (signed char)iq;
        }
        __syncthreads();

        // load my quarter of the new h (4 x ds_read_b128, 64B); quads share
        // the rest via DPP rotations next step
        {
            const uint4* hp = (const uint4*)((const char*)hq + q * 64);
            uint4 a = hp[0], bq = hp[1], cq = hp[2], dq = hp[3];
            hd[0] = a.x;  hd[1] = a.y;  hd[2] = a.z;  hd[3] = a.w;
            hd[4] = bq.x; hd[5] = bq.y; hd[6] = bq.z; hd[7] = bq.w;
            hd[8] = cq.x; hd[9] = cq.y; hd[10] = cq.z; hd[11] = cq.w;
            hd[12] = dq.x; hd[13] = dq.y; hd[14] = dq.z; hd[15] = dq.w;
        }
        xw_c = xw_n;
    }
}

extern "C" void kernel_launch(void* const* d_in, const int* in_sizes, int n_in,
                              void* d_out, int out_size, void* d_ws, size_t ws_size,
                              hipStream_t stream) {
    const float* x  = (const float*)d_in[0];
    const float* Wf = (const float*)d_in[1];
    const float* Uf = (const float*)d_in[2];
    const float* bf = (const float*)d_in[3];
    const float* Wr = (const float*)d_in[4];
    const float* Ur = (const float*)d_in[5];
    const float* br = (const float*)d_in[6];
    float* out = (float*)d_out;

    char* ws = (char*)d_ws;
    unsigned int* UQ = (unsigned int*)ws;                       // 512 KB
    float* Uscale    = (float*)(ws + (size_t)512 * 1024);       // 8 KB
    f16* G           = (f16*)(ws + (size_t)1024 * 1024);        // 128 MB

    prep_uq_kernel<<<8, 256, 0, stream>>>(Uf, Ur, UQ, Uscale);
    dim3 gg(16, 256);
    proj_gemm_kernel<<<gg, 256, 0, stream>>>(x, Wf, Wr, bf, br, G);
    scan_kernel<<<64, 1024, 0, stream>>>(G, UQ, Uscale, out);
}

// Round 3
// 1145.288 us; speedup vs baseline: 1.2297x; 1.2297x over previous
//
#include <hip/hip_runtime.h>
#include <hip/hip_bf16.h>

typedef _Float16 f16;
typedef _Float16 half8 __attribute__((ext_vector_type(8)));
typedef float f32x4 __attribute__((ext_vector_type(4)));

// Problem constants: B=32, S=1024, D=256, H=256, 4H=1024, M=B*S=32768, Ncat=2048

// ---------------- prep: per-column int8 quantization of U (both dirs) -------
// UQ layout: dword index ((dir*16 + kkk)*1024 + j)*4 + e2, kkk=0..15, e2=0..3
// packs U rows k = 16*kkk + 4*e2 + byte  for column j.
__global__ void prep_uq_kernel(const float* __restrict__ Uf, const float* __restrict__ Ur,
                               unsigned int* __restrict__ UQ, float* __restrict__ Uscale)
{
    int idx = blockIdx.x * 256 + threadIdx.x;   // 0..2047 = (dir, j)
    if (idx >= 2048) return;
    int dir = idx >> 10, j = idx & 1023;
    const float* U = dir ? Ur : Uf;
    float m = 0.f;
    for (int k = 0; k < 256; ++k) m = fmaxf(m, fabsf(U[k * 1024 + j]));
    float sinv = (m > 0.f) ? 127.f / m : 0.f;
    for (int kk = 0; kk < 64; ++kk) {
        unsigned int w = 0;
        #pragma unroll
        for (int e = 0; e < 4; ++e) {
            float v = U[(kk * 4 + e) * 1024 + j];
            int q = __float2int_rn(v * sinv);
            w |= ((unsigned int)(q & 0xff)) << (8 * e);
        }
        UQ[(((size_t)dir * 16 + (kk >> 2)) * 1024 + j) * 4 + (kk & 3)] = w;
    }
    Uscale[idx] = m / (127.f * 127.f);  // combined U-scale * h-dequant(1/127)
}

// ---------------- projection GEMM: G[m][n'] = x[m]@W_dir + b_dir (f16) ------
// m = b*1024+s (NOT reversed; reverse handled by scan indexing), n' = dir*1024+g
__global__ __launch_bounds__(256) void proj_gemm_kernel(
    const float* __restrict__ x, const float* __restrict__ Wf, const float* __restrict__ Wr,
    const float* __restrict__ bfw, const float* __restrict__ brw, f16* __restrict__ G)
{
    const int nt = blockIdx.x;           // 0..15  (128-wide n tiles over 2048)
    const int mt = blockIdx.y;           // 0..255 (128-wide m tiles over 32768)
    const int m0 = mt * 128, n0 = nt * 128;
    const int dir = n0 >> 10, nin0 = n0 & 1023;
    const float* W   = dir ? Wr : Wf;
    const float* bia = dir ? brw : bfw;
    __shared__ f16 Asm[128][40];   // [row][k], pad 40 for bank spread
    __shared__ f16 Bsm[128][40];   // [col][k]
    const int t = threadIdx.x;
    const int lane = t & 63, wave = t >> 6;
    const int wr = wave >> 1, wc = wave & 1;      // 2x2 waves, 64x64 each
    f32x4 acc[4][4] = {};
    for (int k0 = 0; k0 < 256; k0 += 32) {
        #pragma unroll
        for (int e = 0; e < 16; ++e) {            // A: 128x32
            int idx = e * 256 + t;
            int r = idx >> 5, kk = idx & 31;
            Asm[r][kk] = (f16)x[(size_t)(m0 + r) * 256 + (k0 + kk)];
        }
        #pragma unroll
        for (int e = 0; e < 16; ++e) {            // B: 32x128 -> [col][k]
            int idx = e * 256 + t;
            int col = idx & 127, kr = idx >> 7;
            Bsm[col][kr] = (f16)W[(size_t)(k0 + kr) * 1024 + (nin0 + col)];
        }
        __syncthreads();
        const int l15 = lane & 15, kb = (lane >> 4) * 8;
        half8 af[4], bfr[4];
        #pragma unroll
        for (int fr = 0; fr < 4; ++fr) af[fr]  = *(const half8*)&Asm[wr * 64 + fr * 16 + l15][kb];
        #pragma unroll
        for (int fc = 0; fc < 4; ++fc) bfr[fc] = *(const half8*)&Bsm[wc * 64 + fc * 16 + l15][kb];
        #pragma unroll
        for (int fr = 0; fr < 4; ++fr)
            #pragma unroll
            for (int fc = 0; fc < 4; ++fc)
                acc[fr][fc] = __builtin_amdgcn_mfma_f32_16x16x32_f16(af[fr], bfr[fc], acc[fr][fc], 0, 0, 0);
        __syncthreads();
    }
    // epilogue: C/D map col=lane&15, row=(lane>>4)*4+i (m89-verified)
    const int row4 = (lane >> 4) * 4, c15 = lane & 15;
    #pragma unroll
    for (int fr = 0; fr < 4; ++fr)
        #pragma unroll
        for (int fc = 0; fc < 4; ++fc) {
            int rbase = m0 + wr * 64 + fr * 16 + row4;
            int cidx  = n0 + wc * 64 + fc * 16 + c15;
            float bv = bia[cidx & 1023];
            #pragma unroll
            for (int i = 0; i < 4; ++i)
                G[(size_t)(rbase + i) * 2048 + cidx] = (f16)(acc[fr][fc][i] + bv);
        }
}

// ---------------- persistent scan: 64 WGs = (dir, batch), 1024 thr ----------
__device__ __forceinline__ int dot4i8(unsigned int a, unsigned int b, int c) {
#if __has_builtin(__builtin_amdgcn_sdot4)
    return __builtin_amdgcn_sdot4(a, b, c, false);
#else
    c += (int)(signed char)(a)       * (int)(signed char)(b);
    c += (int)(signed char)(a >> 8)  * (int)(signed char)(b >> 8);
    c += (int)(signed char)(a >> 16) * (int)(signed char)(b >> 16);
    c += (int)(signed char)(a >> 24) * (int)(signed char)(b >> 24);
    return c;
#endif
}

__device__ __forceinline__ float tanh_fast(float x) {
    float e = __expf(2.f * x);
    return 1.f - 2.f / (e + 1.f);   // exact limits at +-inf, NaN-free
}

// 1024-thread block = 16 waves/CU = exactly 4 waves/EU. Clamp waves_per_eu to
// (4,4): without the max clamp the allocator targets ~10 waves/EU and demotes
// the 64-VGPR U array (round 1/2 showed VGPR_Count=48 => U re-streamed from L2
// every step, ~1940 cy/step). Budget at 4 waves/EU is 128 VGPRs; live set ~105.
__global__
__attribute__((amdgpu_flat_work_group_size(1024, 1024)))
__attribute__((amdgpu_waves_per_eu(4, 4)))
void scan_kernel(
    const f16* __restrict__ G, const unsigned int* __restrict__ UQ,
    const float* __restrict__ Uscale, float* __restrict__ out)
{
    const int wg = blockIdx.x;
    const int dir = wg >> 5, b = wg & 31;
    const int g = threadIdx.x;                 // gate column 0..1023
    __shared__ __align__(16) unsigned int hq[64];   // h int8[256]
    __shared__ float preact[1024];

    // U column g resident in 64 VGPRs (16 x uint4), loaded once
    uint4 ureg[16];
    #pragma unroll
    for (int kkk = 0; kkk < 16; ++kkk)
        ureg[kkk] = *(const uint4*)&UQ[(((size_t)dir * 16 + kkk) * 1024 + g) * 4];
    const float usc = Uscale[dir * 1024 + g];

    float c_state = 0.f;                       // valid for g < 256
    if (g < 64) hq[g] = 0u;                    // h0 = 0
    const long stride = dir ? -2048 : 2048;
    const f16* gp = G + (size_t)b * 1024 * 2048 + dir * 1024 + g
                      + (dir ? (size_t)1023 * 2048 : 0);
    float* outp = out + (size_t)b * 1024 * 512 + dir * 256 + g;  // used by g<256
    f16 xw_c = *gp;                            // prefetch step 0
    __syncthreads();

    for (int t = 0; t < 1024; ++t) {
        const f16* gn = gp + ((t < 1023) ? stride : 0);
        f16 xw_n = *gn;                        // prefetch next step's xW

        int i0 = 0, i1 = 0, i2 = 0, i3 = 0;    // split chain for ILP
        #pragma unroll
        for (int kkk = 0; kkk < 16; ++kkk) {
            uint4 h4 = *(const uint4*)&hq[kkk * 4];   // wave-uniform b128 broadcast
            i0 = dot4i8(ureg[kkk].x, h4.x, i0);
            i1 = dot4i8(ureg[kkk].y, h4.y, i1);
            i2 = dot4i8(ureg[kkk].z, h4.z, i2);
            i3 = dot4i8(ureg[kkk].w, h4.w, i3);
        }
        int iacc = (i0 + i1) + (i2 + i3);
        preact[g] = (float)xw_c + (float)iacc * usc;
        __syncthreads();

        if (g < 256) {
            float pi = preact[g];
            float pf = preact[256 + g];
            float pg = preact[512 + g];
            float po = preact[768 + g];
            float ig = 1.f / (1.f + __expf(-pi));
            float fg = 1.f / (1.f + __expf(-pf));
            float gg = tanh_fast(pg);
            float og = 1.f / (1.f + __expf(-po));
            c_state = fg * c_state + ig * gg;
            float h = og * tanh_fast(c_state);
            int s = dir ? (1023 - t) : t;
            outp[(size_t)s * 512] = h;
            int iq = __float2int_rn(h * 127.f);
            ((signed char*)hq)[g] = (signed char)iq;
        }
        __syncthreads();
        xw_c = xw_n;
        gp = gn;
    }
}

extern "C" void kernel_launch(void* const* d_in, const int* in_sizes, int n_in,
                              void* d_out, int out_size, void* d_ws, size_t ws_size,
                              hipStream_t stream) {
    const float* x  = (const float*)d_in[0];
    const float* Wf = (const float*)d_in[1];
    const float* Uf = (const float*)d_in[2];
    const float* bf = (const float*)d_in[3];
    const float* Wr = (const float*)d_in[4];
    const float* Ur = (const float*)d_in[5];
    const float* br = (const float*)d_in[6];
    float* out = (float*)d_out;

    char* ws = (char*)d_ws;
    unsigned int* UQ = (unsigned int*)ws;                       // 512 KB
    float* Uscale    = (float*)(ws + (size_t)512 * 1024);       // 8 KB
    f16* G           = (f16*)(ws + (size_t)1024 * 1024);        // 128 MB

    prep_uq_kernel<<<8, 256, 0, stream>>>(Uf, Ur, UQ, Uscale);
    dim3 gg(16, 256);
    proj_gemm_kernel<<<gg, 256, 0, stream>>>(x, Wf, Wr, bf, br, G);
    scan_kernel<<<64, 1024, 0, stream>>>(G, UQ, Uscale, out);
}